// Round 1
// 296.612 us; speedup vs baseline: 1.0539x; 1.0539x over previous
//
#include <hip/hip_runtime.h>
#include <math.h>

// Problem constants (from reference): T=4096, N=16, D=512.
#define T_  4096
#define D_  512
#define N_  16
#define S_  32            // number of time segments
#define L_  128           // T_/S_  segment length
#define ND_  (N_*D_)      // 8192 chains
#define SND_ (S_*ND_)     // 262144 segment-threads

// c^L by 7 squarings (L_ = 128). More accurate + cheaper than powf.
__device__ __forceinline__ float pow_L(float c) {
    float r = c * c;   // ^2
    r = r * r;         // ^4
    r = r * r;         // ^8
    r = r * r;         // ^16
    r = r * r;         // ^32
    r = r * r;         // ^64
    r = r * r;         // ^128
    return r;
}

// K1': single pass over x per (s,n,d). Computes, with zero-init states:
//   P  = particular ha solution at segment end        (p_{t+1} = p + a*(x-p))
//   Q0 = particular hv solution at segment end        (q_{t+1} = c*(q + a*e^2), e = x - p)
//   S1 = sum of e_t over the segment
// These suffice to reconstruct hv at any segment start algebraically:
//   hv_L = cL*hv_0 + Q0 - 2*a*cL*S1*ha_0 + cL*(1-cL)*ha_0^2
__global__ __launch_bounds__(256) void k1_seg(const float* __restrict__ x,
                                              const float* __restrict__ alpha,
                                              float* __restrict__ P,
                                              float* __restrict__ Q0,
                                              float* __restrict__ S1) {
    // XCD swizzle: 1024 blocks, 8 XCDs -> each XCD gets 4 contiguous segments,
    // so its L2 only needs 1 MB of x instead of all 8 MB.
    int bid  = blockIdx.x;
    int obid = (bid & 7) * 128 + (bid >> 3);       // bijective: 1024 = 8*128
    int gid  = obid * 256 + threadIdx.x;           // [0, SND_)
    int d    = gid & (D_ - 1);
    int nd   = gid & (ND_ - 1);
    int s    = gid >> 13;                          // / ND_
    float a  = alpha[nd];
    float c  = 1.0f - a;
    float p = 0.0f, q = 0.0f, s1 = 0.0f;
    const float* xp = x + (size_t)s * L_ * D_ + d;
    #pragma unroll 8
    for (int t = 0; t < L_; ++t) {
        float xv = xp[(size_t)t * D_];
        float e  = xv - p;
        q  = c * fmaf(a, e * e, q);                // hv-shape recurrence, zero init
        p  = fmaf(a, e, p);                        // ha-shape recurrence, zero init
        s1 += e;
    }
    P[gid]  = p;
    Q0[gid] = q;
    S1[gid] = s1;
}

// K2': per (n,d) prefix across segments for BOTH ha and hv; writes segment-start
// states in place (haStart over P, hvStart over Q0) and the two finals.
// Safe: each thread owns its nd slots; reads each slot before overwriting it, and
// K1' fully regenerates P/Q0/S1 on every run of the launch sequence.
__global__ __launch_bounds__(256) void k2_prefix(const float* __restrict__ h_a,
                                                 const float* __restrict__ h_s,
                                                 const float* __restrict__ alpha,
                                                 float* __restrict__ P,    // in: P,  out: haStart
                                                 float* __restrict__ Q0,   // in: Q0, out: hvStart
                                                 const float* __restrict__ S1,
                                                 float* __restrict__ out_ha_final,
                                                 float* __restrict__ out_hs_final) {
    int nd   = blockIdx.x * 256 + threadIdx.x;     // [0, ND_)
    float a  = alpha[nd];
    float c  = 1.0f - a;
    float cL = pow_L(c);
    float k1 = 2.0f * a * cL;                      // coeff of S1*H
    float k2 = cL * (1.0f - cL);                   // coeff of H^2  (= a*cL*(1-cL)/(1-c))
    float H  = h_a[nd];
    float hs = h_s[nd];
    float V  = hs * hs;
    #pragma unroll 4
    for (int s = 0; s < S_; ++s) {
        size_t i = (size_t)s * ND_ + nd;
        float p  = P[i];
        float q  = Q0[i];
        float s1 = S1[i];
        P[i]  = H;                                 // haStart for segment s
        Q0[i] = V;                                 // hvStart for segment s
        float Vn = cL * V + q - k1 * s1 * H + k2 * H * H;
        V = fmaxf(Vn, 0.0f);                       // guard cancellation (hv >= 0)
        H = fmaf(cL, H, p);
    }
    out_ha_final[nd] = H;
    out_hs_final[nd] = sqrtf(V);
}

// K5: exact reference recurrence from correct start states; writes out_a/out_s.
// Non-temporal stores: out (268 MB) is write-once — keep it out of L2 so the
// strided x reads stay cached.
__global__ __launch_bounds__(256) void k5_out(const float* __restrict__ x,
                                              const float* __restrict__ alpha,
                                              const float* __restrict__ haStart,
                                              const float* __restrict__ hvStart,
                                              float* __restrict__ out) {
    int bid  = blockIdx.x;
    int obid = (bid & 7) * 128 + (bid >> 3);       // same XCD swizzle as K1'
    int gid  = obid * 256 + threadIdx.x;
    int d    = gid & (D_ - 1);
    int n    = (gid >> 9) & (N_ - 1);
    int nd   = gid & (ND_ - 1);
    int s    = gid >> 13;
    float a  = alpha[nd];
    float c  = 1.0f - a;
    float ha = haStart[gid];
    float hv = hvStart[gid];
    const float* xp = x + (size_t)s * L_ * D_ + d;
    // out row for time t=(s*L_+tt): base (t*2N + n)*D + d ; out_s adds N*D.
    float* oa = out + (size_t)s * L_ * 2 * ND_ + (size_t)n * D_ + d;
    float* os = oa + ND_;
    #pragma unroll 4
    for (int t = 0; t < L_; ++t) {
        float xv = xp[(size_t)t * D_];
        float dd = xv - ha;
        hv = c * fmaf(a, dd * dd, hv);
        ha = fmaf(a, dd, ha);
        __builtin_nontemporal_store(ha, oa + (size_t)t * 2 * ND_);
        __builtin_nontemporal_store(__builtin_amdgcn_sqrtf(hv), os + (size_t)t * 2 * ND_);
    }
}

extern "C" void kernel_launch(void* const* d_in, const int* in_sizes, int n_in,
                              void* d_out, int out_size, void* d_ws, size_t ws_size,
                              hipStream_t stream) {
    const float* x     = (const float*)d_in[0];   // [T, D]
    const float* h_a   = (const float*)d_in[1];   // [N, D]
    const float* h_s   = (const float*)d_in[2];   // [N, D]
    const float* alpha = (const float*)d_in[3];   // [N, D]
    float* out = (float*)d_out;                   // [T, 2N, D] ++ ha_N ++ sqrt(hv_N)

    float* ws = (float*)d_ws;                     // needs 3*SND_ floats = 3 MiB
    float* P  = ws;                               // [S, N, D] -> becomes haStart
    float* Q0 = ws + (size_t)SND_;                // [S, N, D] -> becomes hvStart
    float* S1 = ws + 2 * (size_t)SND_;            // [S, N, D]

    float* out_ha_final = out + (size_t)T_ * 2 * ND_;   // [N, D]
    float* out_hs_final = out_ha_final + ND_;           // [N, D]

    dim3 b(256);
    dim3 segGrid(SND_ / 256);   // 1024 blocks
    dim3 chGrid(ND_ / 256);     // 32 blocks

    k1_seg<<<segGrid, b, 0, stream>>>(x, alpha, P, Q0, S1);
    k2_prefix<<<chGrid, b, 0, stream>>>(h_a, h_s, alpha, P, Q0, S1,
                                        out_ha_final, out_hs_final);
    k5_out<<<segGrid, b, 0, stream>>>(x, alpha, P, Q0, out);
}